// Round 6
// baseline (1002.486 us; speedup 1.0000x reference)
//
#include <hip/hip_runtime.h>
#include <hip/hip_cooperative_groups.h>
namespace cg = cooperative_groups;

#define N_NODES 50000
#define N_EDGES 250000
#define DIM 256          // IN = OUT = H*C
#define ED 194           // edge feature dim
#define EDP 224          // padded to multiple of 32
#define MP_NODE 50048    // 391*128
#define MP_EDGE 250112   // 1954*128

typedef __bf16 bf16x8 __attribute__((ext_vector_type(8)));
typedef float f32x4 __attribute__((ext_vector_type(4)));
typedef short s16x8 __attribute__((ext_vector_type(8)));
typedef short s16x4 __attribute__((ext_vector_type(4)));
typedef unsigned short u16x8 __attribute__((ext_vector_type(8)));

__device__ __forceinline__ float bf2f(unsigned short b){
  union { unsigned int u; float f; } v; v.u = ((unsigned int)b)<<16; return v.f;
}
__device__ __forceinline__ short f2bf(float f){
  union { float f; unsigned int u; } v; v.f = f;
  unsigned int u = v.u;
  return (short)((u + 0x7fffu + ((u>>16)&1u))>>16);
}

// async global->LDS, 16B per lane. LDS dest = wave-uniform base + lane*16.
__device__ __forceinline__ void gload_lds16(const void* g, void* l){
  __builtin_amdgcn_global_load_lds(
      (const __attribute__((address_space(1))) unsigned int*)g,
      (__attribute__((address_space(3))) unsigned int*)l, 16, 0, 0);
}

// ---------------- input converts (fp32 -> bf16, padded) ----------------
// x rows are exactly DIM=256 floats -> flat layout identical in and out.
__global__ __launch_bounds__(256) void convert_x_kernel(
    const float* __restrict__ x, short* __restrict__ xb)
{
  int idx = blockIdx.x*256 + threadIdx.x;       // MP_NODE*64 float4s total
  s16x4 o;
  if (idx < N_NODES*64){
    float4 a = *(const float4*)(x + (size_t)idx*4);
    o[0]=f2bf(a.x); o[1]=f2bf(a.y); o[2]=f2bf(a.z); o[3]=f2bf(a.w);
  } else {
    o[0]=0; o[1]=0; o[2]=0; o[3]=0;
  }
  *(s16x4*)(xb + (size_t)idx*4) = o;
}

// Edge rows are 194 floats (776B, only 8B-aligned) -> stage 32 rows through
// LDS with dense flat float4 loads, then convert+pad with coalesced stores.
#define E_ROWS 32
__global__ __launch_bounds__(256) void convert_e_kernel(
    const float* __restrict__ ea, short* __restrict__ eb)
{
  __shared__ float lds[E_ROWS*ED];              // 6208 floats = 24832 B
  int row0 = blockIdx.x * E_ROWS;
  int tid = threadIdx.x;
  int base = row0 * ED;                         // float index of block start
  int valid = N_EDGES*ED - base;                // may be <=0 for pad blocks

  for (int i = tid; i < E_ROWS*ED/4; i += 256){
    float4 v;
    if (i*4 < valid) v = *(const float4*)(ea + base + i*4);
    else             v = make_float4(0.f,0.f,0.f,0.f);
    *(float4*)(lds + i*4) = v;
  }
  __syncthreads();

  for (int u = tid; u < E_ROWS*28; u += 256){
    int row = u / 28;
    int c8  = u - row*28;
    int col = c8*8;
    s16x8 o;
    if (col + 8 <= ED){
      #pragma unroll
      for (int j2=0;j2<4;j2++){
        float2 f = *(const float2*)(lds + row*ED + col + j2*2);
        o[j2*2]   = f2bf(f.x);
        o[j2*2+1] = f2bf(f.y);
      }
    } else {
      #pragma unroll
      for (int j=0;j<8;j++){
        int c = col + j;
        o[j] = (c < ED) ? f2bf(lds[row*ED + c]) : (short)0;
      }
    }
    *(s16x8*)(eb + (size_t)(row0+row)*EDP + col) = o;
  }
}

// ---------------- fused weight prep: BOTH convs, one launch (162 blocks) ----
// per conv: blocks 0..63 node-W 64x64 tile transpose via padded LDS,
// blocks 64..79 edge-W transpose (zero-pad k>=ED), block 80 bias concat.
__global__ __launch_bounds__(256) void prep_weights_all(
    const float* __restrict__ Wq1, const float* __restrict__ Wk1,
    const float* __restrict__ Wv1, const float* __restrict__ Ws1,
    const float* __restrict__ We1,
    const float* __restrict__ bq1, const float* __restrict__ bk1,
    const float* __restrict__ bv1, const float* __restrict__ bs1,
    const float* __restrict__ Wq2, const float* __restrict__ Wk2,
    const float* __restrict__ Wv2, const float* __restrict__ Ws2,
    const float* __restrict__ We2,
    const float* __restrict__ bq2, const float* __restrict__ bk2,
    const float* __restrict__ bv2, const float* __restrict__ bs2,
    short* __restrict__ WtN1, short* __restrict__ WtE1, float* __restrict__ biasN1,
    short* __restrict__ WtN2, short* __restrict__ WtE2, float* __restrict__ biasN2)
{
  __shared__ short lds[64*65];
  int b = blockIdx.x, tid = threadIdx.x;
  const float *Wq,*Wk,*Wv,*Ws,*We,*b0,*b1,*b2,*b3;
  short *WtN,*WtE; float* biasN;
  if (b < 81){
    Wq=Wq1;Wk=Wk1;Wv=Wv1;Ws=Ws1;We=We1;b0=bq1;b1=bk1;b2=bv1;b3=bs1;
    WtN=WtN1;WtE=WtE1;biasN=biasN1;
  } else {
    b -= 81;
    Wq=Wq2;Wk=Wk2;Wv=Wv2;Ws=Ws2;We=We2;b0=bq2;b1=bk2;b2=bv2;b3=bs2;
    WtN=WtN2;WtE=WtE2;biasN=biasN2;
  }
  if (b < 64){
    int mat = b>>4, tile = b&15;
    int i0 = (tile>>2)*64, o0 = (tile&3)*64;
    const float* W = (mat==0)?Wq:((mat==1)?Wk:((mat==2)?Wv:Ws));
    #pragma unroll
    for (int t=0;t<16;t++){
      int idx = t*256+tid; int r = idx>>6, c = idx&63;
      lds[r*65+c] = f2bf(W[(size_t)(i0+r)*256 + o0 + c]);
    }
    __syncthreads();
    #pragma unroll
    for (int t=0;t<4;t++){
      int idx = t*256+tid; int r = idx>>4, c4 = (idx&15)*4;
      s16x4 o;
      o[0]=lds[(c4+0)*65+r]; o[1]=lds[(c4+1)*65+r];
      o[2]=lds[(c4+2)*65+r]; o[3]=lds[(c4+3)*65+r];
      *(s16x4*)(WtN + (mat<<16) + (o0+r)*256 + i0 + c4) = o;
    }
  } else if (b < 80){
    int b2 = b-64;
    int k0 = (b2>>2)*64, o0 = (b2&3)*64;
    #pragma unroll
    for (int t=0;t<16;t++){
      int idx = t*256+tid; int r = idx>>6, c = idx&63;
      int k = k0+r;
      lds[r*65+c] = (k<ED) ? f2bf(We[(size_t)k*256 + o0 + c]) : (short)0;
    }
    __syncthreads();
    #pragma unroll
    for (int t=0;t<4;t++){
      int idx = t*256+tid; int r = idx>>4, c4 = (idx&15)*4;
      if (k0 + c4 < EDP){
        s16x4 o;
        o[0]=lds[(c4+0)*65+r]; o[1]=lds[(c4+1)*65+r];
        o[2]=lds[(c4+2)*65+r]; o[3]=lds[(c4+3)*65+r];
        *(s16x4*)(WtE + (o0+r)*EDP + k0 + c4) = o;
      }
    }
  } else {
    for (int t = tid; t < 1024; t += 256){
      const float* bb = (t<256)?b0:((t<512)?b1:((t<768)?b2:b3));
      biasN[t] = bb[t&255];
    }
  }
}

// ---------------- CSR build: ONE cooperative kernel (replaces 5 launches) ----
// 196 blocks x 256 threads, grid-stride over edges for count/scatter, each
// block owns 256 nodes for the scan. Grid syncs order the phases.
#define CSR_NBLK 196
__global__ __launch_bounds__(256) void build_csr_coop(
    const int* __restrict__ src, const int* __restrict__ dst,
    int* __restrict__ deg, int* __restrict__ part,
    int* __restrict__ rowptr, int* __restrict__ cursor, int2* __restrict__ csr)
{
  cg::grid_group grid = cg::this_grid();
  __shared__ int s[256];
  int t = threadIdx.x, b = blockIdx.x;
  int gid = b*256 + t;
  // phase 0: zero deg
  for (int i = gid; i < N_NODES; i += CSR_NBLK*256) deg[i] = 0;
  grid.sync();
  // phase 1: count in-degrees
  for (int e = gid; e < N_EDGES; e += CSR_NBLK*256) atomicAdd(&deg[dst[e]], 1);
  grid.sync();
  // phase 2: block-local inclusive scan over this block's 256 nodes
  int i = gid;
  int v = (i < N_NODES) ? deg[i] : 0;
  s[t] = v; __syncthreads();
  for (int off=1; off<256; off<<=1){
    int x = (t>=off) ? s[t-off] : 0;
    __syncthreads();
    s[t] += x;
    __syncthreads();
  }
  int local = s[t];
  if (t == 255) part[b] = s[255];
  grid.sync();
  // phase 3: block 0 exclusive-scans the 196 block totals
  if (b == 0){
    int pv = (t < CSR_NBLK) ? part[t] : 0;
    __syncthreads();               // s reuse hazard guard
    s[t] = pv; __syncthreads();
    for (int off=1; off<256; off<<=1){
      int x = (t>=off) ? s[t-off] : 0;
      __syncthreads();
      s[t] += x;
      __syncthreads();
    }
    part[t] = (t==0) ? 0 : s[t-1];
  }
  grid.sync();
  // phase 4: rowptr + cursor
  int boff = part[b];
  if (i < N_NODES){ rowptr[i+1] = boff + local; cursor[i] = 0; }
  if (gid == 0) rowptr[0] = 0;
  grid.sync();
  // phase 5: scatter (premultiplied byte offsets: src*2048 = QKVS row, e*512 = Eemb row)
  for (int e = gid; e < N_EDGES; e += CSR_NBLK*256){
    int d = dst[e];
    int pos = atomicAdd(&cursor[d], 1);
    csr[rowptr[d] + pos] = make_int2(src[e]<<11, e<<9);
  }
}

// ---------------- tiled GEMM: out = A(bf16,[Mpad][K]) @ Bt^T (Bt=[N][K] bf16) ----
// r2-proven structure: 128x128 tile, 4 waves, row-major LDS [row][32k], staging
// 4-lane-contiguous-64B global reads. (Fragment-major staging permutation was
// tried in r5 and REGRESSED ~35us: same LDS bank behavior, worse VMEM lane->addr
// coalescing. 128x256 tile REGRESSED: occupancy collapse. Keep this shape.)
template<int K, int NLD, bool HAS_BIAS>
__global__ __launch_bounds__(256) void gemm_bt(
    const short* __restrict__ A, const short* __restrict__ Bt,
    const float* __restrict__ bias, short* __restrict__ out, int M)
{
  __shared__ short As[128*32];
  __shared__ short Bs[128*32];
  int tid = threadIdx.x;
  int lane = tid & 63, wave = tid >> 6;
  int m0 = blockIdx.x*128, n0 = blockIdx.y*128;

  int srow = tid>>2, scol = (tid&3)*8;
  const short* gA = A + (size_t)(m0+srow)*K + scol;
  const short* gB = Bt + (size_t)(n0+srow)*K + scol;
  short* ldsA1 = As + wave*512;
  short* ldsA2 = As + 2048 + wave*512;
  short* ldsB1 = Bs + wave*512;
  short* ldsB2 = Bs + 2048 + wave*512;

  int wr = wave>>1, wc = wave&1;
  int fr = lane & 15;
  int kq = lane >> 4;
  f32x4 acc[4][4];
  #pragma unroll
  for (int a=0;a<4;a++)
    #pragma unroll
    for (int b=0;b<4;b++) acc[a][b] = (f32x4){0.f,0.f,0.f,0.f};

  for (int k0=0; k0<K; k0+=32){
    __syncthreads();
    gload_lds16(gA + k0,                ldsA1);
    gload_lds16(gA + (size_t)64*K + k0, ldsA2);
    gload_lds16(gB + k0,                ldsB1);
    gload_lds16(gB + (size_t)64*K + k0, ldsB2);
    __syncthreads();

    bf16x8 af[4], bf[4];
    const short* ar = As + (wr*64 + fr)*32 + kq*8;
    const short* br = Bs + (wc*64 + fr)*32 + kq*8;
    #pragma unroll
    for (int fm=0;fm<4;fm++) af[fm] = *(const bf16x8*)(ar + fm*512);
    #pragma unroll
    for (int fn=0;fn<4;fn++) bf[fn] = *(const bf16x8*)(br + fn*512);
    #pragma unroll
    for (int fm=0;fm<4;fm++)
      #pragma unroll
      for (int fn=0;fn<4;fn++)
        acc[fm][fn] = __builtin_amdgcn_mfma_f32_16x16x32_bf16(af[fm], bf[fn], acc[fm][fn], 0, 0, 0);
  }

  int cr = (lane>>4)*4;
  int cc = lane & 15;
  #pragma unroll
  for (int fm=0;fm<4;fm++){
    #pragma unroll
    for (int fn=0;fn<4;fn++){
      int col = n0 + wc*64 + fn*16 + cc;
      float bv = HAS_BIAS ? bias[col] : 0.f;
      #pragma unroll
      for (int i=0;i<4;i++){
        int row = m0 + wr*64 + fm*16 + cr + i;
        if (row < M) out[(size_t)row*NLD + col] = f2bf(acc[fm][fn][i] + bv);
      }
    }
  }
}

// ---------------- fused edge phase ----------------
// ONE WAVE PER NODE (4 nodes per block, no __syncthreads, no LDS merge).
// 32 lanes per edge, 8 channels per lane (16B loads), TWO edges in flight
// (half = lane>>5). Tail via clamped csr index + p=0. Cross-half merge via
// shfl_xor(32) — registers only.
// (4-edge unroll REGRESSED: avg degree 5 -> +33% wasted clamped-duplicate loads.)
__global__ __launch_bounds__(256) void edge_phase_kernel(
    const short* __restrict__ QKVS, const short* __restrict__ Eemb,
    const int* __restrict__ rowptr, const int2* __restrict__ csr,
    short* __restrict__ out_bf, float* __restrict__ out_f, int relu)
{
  int tid = threadIdx.x, wave = tid>>6, lane = tid&63;
  int node = blockIdx.x*4 + wave;
  if (node >= N_NODES){
    if (node < MP_NODE && out_bf){
      s16x4 z; z[0]=0; z[1]=0; z[2]=0; z[3]=0;
      *(s16x4*)(out_bf + (size_t)node*256 + lane*4) = z;
    }
    return;
  }
  int half = lane>>5;          // which edge of the pair
  int hl   = lane&31;          // channel-group 0..31 (8 ch each)
  int c8   = hl*8;
  const unsigned short* base = (const unsigned short*)QKVS + (size_t)node*1024;

  u16x8 qu = *(const u16x8*)(base + c8);
  float q[8];
  #pragma unroll
  for (int j=0;j<8;j++) q[j] = bf2f(qu[j])*0.125f;

  int beg = rowptr[node], end = rowptr[node+1];
  float l = 0.f;
  float a[8];
  #pragma unroll
  for (int j=0;j<8;j++) a[j] = 0.f;
  int kb = 512 + hl*16;        // K byte offset within QKVS row for this lane
  int ebo = hl*16;             // Eemb byte offset

  for (int idx = beg; idx < end; idx += 2){
    int j = idx + half;
    int jc = (j < end) ? j : (end-1);
    int2 se = csr[jc];         // .x = src*2048 bytes, .y = e*512 bytes
    const char* Kp = (const char*)QKVS + (unsigned)(se.x + kb);
    const char* Ep = (const char*)Eemb + (unsigned)(se.y + ebo);
    u16x8 ku = *(const u16x8*)Kp;
    u16x8 vu = *(const u16x8*)(Kp + 512);   // V block
    u16x8 eu = *(const u16x8*)Ep;
    float vv[8];
    float t = 0.f;
    #pragma unroll
    for (int c=0;c<8;c++){
      float ef = bf2f(eu[c]);
      float kf = bf2f(ku[c]) + ef;
      vv[c]    = bf2f(vu[c]) + ef;
      t += q[c]*kf;
    }
    t += __shfl_xor(t, 1, 64);
    t += __shfl_xor(t, 2, 64);
    t += __shfl_xor(t, 4, 64);
    float p = (j < end) ? __expf(t) : 0.f;
    l += p;
    #pragma unroll
    for (int c=0;c<8;c++) a[c] += p*vv[c];
  }

  // merge the two halves (each summed a disjoint subset of edges)
  l += __shfl_xor(l, 32, 64);
  #pragma unroll
  for (int c=0;c<8;c++) a[c] += __shfl_xor(a[c], 32, 64);

  float inv = (l > 0.f) ? 1.0f/l : 0.f;
  u16x8 su = *(const u16x8*)(base + 768 + c8);   // skip = x@Ws + bs
  float r[8];
  #pragma unroll
  for (int c=0;c<8;c++){
    float v = a[c]*inv + bf2f(su[c]);
    r[c] = relu ? fmaxf(v, 0.f) : v;
  }

  if (out_bf){
    if (!half){
      s16x8 o;
      #pragma unroll
      for (int c=0;c<8;c++) o[c] = f2bf(r[c]);
      *(s16x8*)(out_bf + (size_t)node*256 + c8) = o;
    }
  } else {
    float4 st = half ? make_float4(r[4],r[5],r[6],r[7])
                     : make_float4(r[0],r[1],r[2],r[3]);
    *(float4*)(out_f + (size_t)node*256 + c8 + half*4) = st;
  }
}

// ---------------- launch ----------------
extern "C" void kernel_launch(void* const* d_in, const int* in_sizes, int n_in,
                              void* d_out, int out_size, void* d_ws, size_t ws_size,
                              hipStream_t stream)
{
  const float* x     = (const float*)d_in[0];
  const int*   eidx  = (const int*)d_in[1];
  const float* eattr = (const float*)d_in[2];
  const float* Wq1=(const float*)d_in[3],  *bq1=(const float*)d_in[4];
  const float* Wk1=(const float*)d_in[5],  *bk1=(const float*)d_in[6];
  const float* Wv1=(const float*)d_in[7],  *bv1=(const float*)d_in[8];
  const float* We1=(const float*)d_in[9];
  const float* Ws1=(const float*)d_in[10], *bs1=(const float*)d_in[11];
  const float* Wq2=(const float*)d_in[12], *bq2=(const float*)d_in[13];
  const float* Wk2=(const float*)d_in[14], *bk2=(const float*)d_in[15];
  const float* Wv2=(const float*)d_in[16], *bv2=(const float*)d_in[17];
  const float* We2=(const float*)d_in[18];
  const float* Ws2=(const float*)d_in[19], *bs2=(const float*)d_in[20];

  char* ws = (char*)d_ws;
  size_t off = 0;
  auto alloc = [&](size_t bytes)->char*{
    char* p = ws + off; off = (off + bytes + 255) & ~(size_t)255; return p;
  };
  short* QKVS  = (short*)alloc((size_t)N_NODES*1024*2);
  short* Eemb  = (short*)alloc((size_t)N_EDGES*256*2);
  short* x_bf  = (short*)alloc((size_t)MP_NODE*DIM*2);
  short* h_bf  = (short*)alloc((size_t)MP_NODE*DIM*2);
  short* e_bf  = (short*)alloc((size_t)MP_EDGE*EDP*2);
  short* WtN1  = (short*)alloc((size_t)4*65536*2);
  short* WtE1  = (short*)alloc((size_t)256*EDP*2);
  float* biasN1= (float*)alloc((size_t)1024*4);
  short* WtN2  = (short*)alloc((size_t)4*65536*2);
  short* WtE2  = (short*)alloc((size_t)256*EDP*2);
  float* biasN2= (float*)alloc((size_t)1024*4);
  int*   deg   = (int*)alloc((size_t)N_NODES*4);
  int*   rowptr= (int*)alloc((size_t)(N_NODES+1)*4);
  int*   cursor= (int*)alloc((size_t)N_NODES*4);
  int*   part  = (int*)alloc((size_t)256*4);
  int2*  csr   = (int2*)alloc((size_t)N_EDGES*8);

  const int* srcp = eidx;
  const int* dstp = eidx + N_EDGES;

  convert_x_kernel<<<MP_NODE*64/256,256,0,stream>>>(x, x_bf);
  convert_e_kernel<<<MP_EDGE/E_ROWS,256,0,stream>>>(eattr, e_bf);

  {
    const int* srcp_ = srcp; const int* dstp_ = dstp;
    int* deg_ = deg; int* part_ = part; int* rowptr_ = rowptr; int* cursor_ = cursor;
    int2* csr_ = csr;
    void* cargs[] = { &srcp_, &dstp_, &deg_, &part_, &rowptr_, &cursor_, &csr_ };
    hipLaunchCooperativeKernel((void*)build_csr_coop, dim3(CSR_NBLK,1,1),
                               dim3(256,1,1), cargs, 0, stream);
  }

  prep_weights_all<<<162,256,0,stream>>>(
      Wq1,Wk1,Wv1,Ws1,We1,bq1,bk1,bv1,bs1,
      Wq2,Wk2,Wv2,Ws2,We2,bq2,bk2,bv2,bs2,
      WtN1,WtE1,biasN1, WtN2,WtE2,biasN2);

  // ---- conv1 ----
  gemm_bt<DIM,1024,true><<<dim3(MP_NODE/128,8),256,0,stream>>>(x_bf, WtN1, biasN1, QKVS, N_NODES);
  gemm_bt<EDP,256,false><<<dim3(MP_EDGE/128,2),256,0,stream>>>(e_bf, WtE1, nullptr, Eemb, N_EDGES);
  edge_phase_kernel<<<MP_NODE/4,256,0,stream>>>(QKVS,Eemb,rowptr,csr,h_bf,nullptr,1);

  // ---- conv2 ----
  gemm_bt<DIM,1024,true><<<dim3(MP_NODE/128,8),256,0,stream>>>(h_bf, WtN2, biasN2, QKVS, N_NODES);
  gemm_bt<EDP,256,false><<<dim3(MP_EDGE/128,2),256,0,stream>>>(e_bf, WtE2, nullptr, Eemb, N_EDGES);
  edge_phase_kernel<<<N_NODES/4,256,0,stream>>>(QKVS,Eemb,rowptr,csr,nullptr,(float*)d_out,0);
}

// Round 7
// 887.928 us; speedup vs baseline: 1.1290x; 1.1290x over previous
//
#include <hip/hip_runtime.h>

#define N_NODES 50000
#define N_EDGES 250000
#define DIM 256          // IN = OUT = H*C
#define ED 194           // edge feature dim
#define EDP 224          // padded to multiple of 32
#define MP_NODE 50048    // 391*128
#define MP_EDGE 250112   // 1954*128

typedef __bf16 bf16x8 __attribute__((ext_vector_type(8)));
typedef float f32x4 __attribute__((ext_vector_type(4)));
typedef short s16x8 __attribute__((ext_vector_type(8)));
typedef short s16x4 __attribute__((ext_vector_type(4)));
typedef unsigned short u16x8 __attribute__((ext_vector_type(8)));

__device__ __forceinline__ float bf2f(unsigned short b){
  union { unsigned int u; float f; } v; v.u = ((unsigned int)b)<<16; return v.f;
}
__device__ __forceinline__ short f2bf(float f){
  union { float f; unsigned int u; } v; v.f = f;
  unsigned int u = v.u;
  return (short)((u + 0x7fffu + ((u>>16)&1u))>>16);
}

// async global->LDS, 16B per lane. LDS dest = wave-uniform base + lane*16.
__device__ __forceinline__ void gload_lds16(const void* g, void* l){
  __builtin_amdgcn_global_load_lds(
      (const __attribute__((address_space(1))) unsigned int*)g,
      (__attribute__((address_space(3))) unsigned int*)l, 16, 0, 0);
}

// ---------------- input converts (fp32 -> bf16, padded) ----------------
__global__ __launch_bounds__(256) void convert_x_kernel(
    const float* __restrict__ x, short* __restrict__ xb)
{
  int idx = blockIdx.x*256 + threadIdx.x;       // MP_NODE*64 float4s total
  s16x4 o;
  if (idx < N_NODES*64){
    float4 a = *(const float4*)(x + (size_t)idx*4);
    o[0]=f2bf(a.x); o[1]=f2bf(a.y); o[2]=f2bf(a.z); o[3]=f2bf(a.w);
  } else {
    o[0]=0; o[1]=0; o[2]=0; o[3]=0;
  }
  *(s16x4*)(xb + (size_t)idx*4) = o;
}

// Edge rows are 194 floats (776B, only 8B-aligned) -> stage 32 rows through
// LDS with dense flat float4 loads, then convert+pad with coalesced stores.
#define E_ROWS 32
__global__ __launch_bounds__(256) void convert_e_kernel(
    const float* __restrict__ ea, short* __restrict__ eb)
{
  __shared__ float lds[E_ROWS*ED];              // 6208 floats = 24832 B
  int row0 = blockIdx.x * E_ROWS;
  int tid = threadIdx.x;
  int base = row0 * ED;                         // float index of block start
  int valid = N_EDGES*ED - base;                // may be <=0 for pad blocks

  for (int i = tid; i < E_ROWS*ED/4; i += 256){
    float4 v;
    if (i*4 < valid) v = *(const float4*)(ea + base + i*4);
    else             v = make_float4(0.f,0.f,0.f,0.f);
    *(float4*)(lds + i*4) = v;
  }
  __syncthreads();

  for (int u = tid; u < E_ROWS*28; u += 256){
    int row = u / 28;
    int c8  = u - row*28;
    int col = c8*8;
    s16x8 o;
    if (col + 8 <= ED){
      #pragma unroll
      for (int j2=0;j2<4;j2++){
        float2 f = *(const float2*)(lds + row*ED + col + j2*2);
        o[j2*2]   = f2bf(f.x);
        o[j2*2+1] = f2bf(f.y);
      }
    } else {
      #pragma unroll
      for (int j=0;j<8;j++){
        int c = col + j;
        o[j] = (c < ED) ? f2bf(lds[row*ED + c]) : (short)0;
      }
    }
    *(s16x8*)(eb + (size_t)(row0+row)*EDP + col) = o;
  }
}

// ---------------- weight transforms (coalesced reads) ----------------
// WtN layout: [w][o][i] == B^T[n][k], n = w*256+o  (bf16)
__global__ __launch_bounds__(256) void transpose_node_w(
    const float* __restrict__ Wq, const float* __restrict__ Wk,
    const float* __restrict__ Wv, const float* __restrict__ Ws,
    short* __restrict__ WtN)
{
  int idx = blockIdx.x*256 + threadIdx.x;      // 4*65536 total
  int w = idx>>16, rem = idx&65535;
  int i = rem>>8, o = rem&255;                 // o fast -> coalesced read
  const float* W = (w==0)?Wq:((w==1)?Wk:((w==2)?Wv:Ws));
  WtN[(w<<16) + o*256 + i] = f2bf(W[i*256+o]);
}
__global__ __launch_bounds__(256) void bias_cat_kernel(
    const float* __restrict__ b0, const float* __restrict__ b1,
    const float* __restrict__ b2, const float* __restrict__ b3,
    float* __restrict__ biasN)
{
  int t = blockIdx.x*256 + threadIdx.x;        // 1024
  const float* b = (t<256)?b0:((t<512)?b1:((t<768)?b2:b3));
  biasN[t] = b[t&255];
}
// WtE layout: [o][k] padded to EDP with zeros (bf16)
__global__ __launch_bounds__(256) void transpose_edge_w(
    const float* __restrict__ We, short* __restrict__ WtE)
{
  int idx = blockIdx.x*256 + threadIdx.x;      // 224*256 total
  int k = idx>>8, o = idx&255;                 // o fast -> coalesced read
  WtE[o*EDP + k] = (k<ED) ? f2bf(We[k*256+o]) : (short)0;
}

// ---------------- CSR build ----------------
__global__ __launch_bounds__(256) void zero_ints(int* __restrict__ p, int n){
  int i = blockIdx.x*256 + threadIdx.x;
  if (i<n) p[i] = 0;
}
__global__ __launch_bounds__(256) void count_deg(const int* __restrict__ dst, int* __restrict__ deg){
  int e = blockIdx.x*256 + threadIdx.x;
  if (e < N_EDGES) atomicAdd(&deg[dst[e]], 1);
}
#define SCAN_NBLK 196
__global__ __launch_bounds__(256) void scan_p1(const int* __restrict__ deg, int* __restrict__ part){
  int t = threadIdx.x;
  int i = blockIdx.x*256 + t;
  int v = (i<N_NODES)? deg[i] : 0;
  #pragma unroll
  for (int off=32; off; off>>=1) v += __shfl_xor(v, off, 64);
  __shared__ int s[4];
  if ((t&63)==0) s[t>>6] = v;
  __syncthreads();
  if (t==0) part[blockIdx.x] = s[0]+s[1]+s[2]+s[3];
}
__global__ __launch_bounds__(256) void scan_p2(int* __restrict__ part){
  __shared__ int s[256];
  int t = threadIdx.x;
  int v = (t<SCAN_NBLK)? part[t] : 0;
  s[t] = v; __syncthreads();
  for (int off=1; off<256; off<<=1){
    int x = (t>=off)? s[t-off] : 0;
    __syncthreads();
    s[t] += x;
    __syncthreads();
  }
  part[t] = (t==0)? 0 : s[t-1];
}
// also zeroes cursor
__global__ __launch_bounds__(256) void scan_p3(const int* __restrict__ deg,
    const int* __restrict__ part, int* __restrict__ rowptr, int* __restrict__ cursor){
  __shared__ int s[256];
  int t = threadIdx.x;
  int i = blockIdx.x*256 + t;
  int v = (i<N_NODES)? deg[i] : 0;
  s[t] = v; __syncthreads();
  for (int off=1; off<256; off<<=1){
    int x = (t>=off)? s[t-off] : 0;
    __syncthreads();
    s[t] += x;
    __syncthreads();
  }
  if (i < N_NODES){ rowptr[i+1] = part[blockIdx.x] + s[t]; cursor[i] = 0; }
  if (i == 0) rowptr[0] = 0;
}
// csrx[pos] = src*2048 (QKVS row byte offset); eperm[pos] = edge id.
// Eemb is later WRITTEN in csr order, so edge_phase's E-address is just pos<<9.
__global__ __launch_bounds__(256) void scatter_edges(
    const int* __restrict__ src, const int* __restrict__ dst,
    const int* __restrict__ rowptr, int* __restrict__ cursor,
    int* __restrict__ csrx, int* __restrict__ eperm)
{
  int e = blockIdx.x*256 + threadIdx.x;
  if (e < N_EDGES){
    int d = dst[e];
    int pos = atomicAdd(&cursor[d], 1);
    int p = rowptr[d] + pos;
    csrx[p] = src[e]<<11;
    eperm[p] = e;
  }
}

// ---------------- tiled GEMM: out = A(bf16,[Mpad][K]) @ Bt^T (Bt=[N][K] bf16) ----
// r2-proven structure: 128x128 tile, 4 waves, row-major LDS [row][32k], staging
// 4-lane-contiguous-64B global reads.
// PERM variant (edge GEMM): A row r is sourced from perm[r] so the OUTPUT rows
// land in CSR order -> edge_phase streams Eemb sequentially. Per k-step each
// row still reads 64B contiguous; all 7 chunks of a row are consumed by the
// same block, so scattering rows wastes no HBM lines (L2 absorbs 128B fetches).
// (Fragment-major staging REGRESSED r5: worse VMEM coalescing. 128x256 tile
// REGRESSED r4: occupancy collapse. Cooperative CSR REGRESSED r6: grid.sync
// ~20us each. Keep this shape.)
template<int K, int NLD, bool HAS_BIAS, bool PERM>
__global__ __launch_bounds__(256) void gemm_bt(
    const short* __restrict__ A, const short* __restrict__ Bt,
    const float* __restrict__ bias, short* __restrict__ out, int M,
    const int* __restrict__ perm)
{
  __shared__ short As[128*32];
  __shared__ short Bs[128*32];
  int tid = threadIdx.x;
  int lane = tid & 63, wave = tid >> 6;
  int m0 = blockIdx.x*128, n0 = blockIdx.y*128;

  int srow = tid>>2, scol = (tid&3)*8;
  int arow = m0 + srow;
  if (PERM) arow = (arow < M) ? perm[arow] : 0;
  int arow2 = m0 + 64 + srow;
  if (PERM) arow2 = (arow2 < M) ? perm[arow2] : 0;
  const short* gA  = A + (size_t)arow*K + scol;
  const short* gA2 = A + (size_t)arow2*K + scol;
  const short* gB = Bt + (size_t)(n0+srow)*K + scol;
  short* ldsA1 = As + wave*512;
  short* ldsA2 = As + 2048 + wave*512;
  short* ldsB1 = Bs + wave*512;
  short* ldsB2 = Bs + 2048 + wave*512;

  int wr = wave>>1, wc = wave&1;
  int fr = lane & 15;
  int kq = lane >> 4;
  f32x4 acc[4][4];
  #pragma unroll
  for (int a=0;a<4;a++)
    #pragma unroll
    for (int b=0;b<4;b++) acc[a][b] = (f32x4){0.f,0.f,0.f,0.f};

  for (int k0=0; k0<K; k0+=32){
    __syncthreads();
    gload_lds16(gA + k0,  ldsA1);
    gload_lds16(PERM ? (gA2 + k0) : (gA + (size_t)64*K + k0), ldsA2);
    gload_lds16(gB + k0,                ldsB1);
    gload_lds16(gB + (size_t)64*K + k0, ldsB2);
    __syncthreads();

    bf16x8 af[4], bf[4];
    const short* ar = As + (wr*64 + fr)*32 + kq*8;
    const short* br = Bs + (wc*64 + fr)*32 + kq*8;
    #pragma unroll
    for (int fm=0;fm<4;fm++) af[fm] = *(const bf16x8*)(ar + fm*512);
    #pragma unroll
    for (int fn=0;fn<4;fn++) bf[fn] = *(const bf16x8*)(br + fn*512);
    #pragma unroll
    for (int fm=0;fm<4;fm++)
      #pragma unroll
      for (int fn=0;fn<4;fn++)
        acc[fm][fn] = __builtin_amdgcn_mfma_f32_16x16x32_bf16(af[fm], bf[fn], acc[fm][fn], 0, 0, 0);
  }

  int cr = (lane>>4)*4;
  int cc = lane & 15;
  #pragma unroll
  for (int fm=0;fm<4;fm++){
    #pragma unroll
    for (int fn=0;fn<4;fn++){
      int col = n0 + wc*64 + fn*16 + cc;
      float bv = HAS_BIAS ? bias[col] : 0.f;
      #pragma unroll
      for (int i=0;i<4;i++){
        int row = m0 + wr*64 + fm*16 + cr + i;
        if (row < M) out[(size_t)row*NLD + col] = f2bf(acc[fm][fn][i] + bv);
      }
    }
  }
}

// ---------------- fused edge phase ----------------
// ONE WAVE PER NODE (4 nodes per block). 32 lanes per edge, 8 ch/lane (16B
// loads), TWO edges in flight (half = lane>>5). Eemb is stored in CSR order:
// E-address = pos<<9 (no dependency on the csr load; reads stream
// sequentially). Tail via clamped csr index + p=0. Cross-half merge via
// shfl_xor(32).
// (4-edge unroll REGRESSED: +33% wasted clamped-duplicate loads at avg deg 5.)
__global__ __launch_bounds__(256) void edge_phase_kernel(
    const short* __restrict__ QKVS, const short* __restrict__ Eemb,
    const int* __restrict__ rowptr, const int* __restrict__ csrx,
    short* __restrict__ out_bf, float* __restrict__ out_f, int relu)
{
  int tid = threadIdx.x, wave = tid>>6, lane = tid&63;
  int node = blockIdx.x*4 + wave;
  if (node >= N_NODES){
    if (node < MP_NODE && out_bf){
      s16x4 z; z[0]=0; z[1]=0; z[2]=0; z[3]=0;
      *(s16x4*)(out_bf + (size_t)node*256 + lane*4) = z;
    }
    return;
  }
  int half = lane>>5;          // which edge of the pair
  int hl   = lane&31;          // channel-group 0..31 (8 ch each)
  int c8   = hl*8;
  const unsigned short* base = (const unsigned short*)QKVS + (size_t)node*1024;

  u16x8 qu = *(const u16x8*)(base + c8);
  float q[8];
  #pragma unroll
  for (int j=0;j<8;j++) q[j] = bf2f(qu[j])*0.125f;

  int beg = rowptr[node], end = rowptr[node+1];
  float l = 0.f;
  float a[8];
  #pragma unroll
  for (int j=0;j<8;j++) a[j] = 0.f;
  int kb = 512 + hl*16;        // K byte offset within QKVS row for this lane
  int ebo = hl*16;             // Eemb byte offset within row

  for (int idx = beg; idx < end; idx += 2){
    int j = idx + half;
    int jc = (j < end) ? j : (end-1);
    int sx = csrx[jc];                         // src*2048 bytes
    const char* Ep = (const char*)Eemb + ((unsigned)(jc<<9) + ebo);
    const char* Kp = (const char*)QKVS + (unsigned)(sx + kb);
    u16x8 eu = *(const u16x8*)Ep;
    u16x8 ku = *(const u16x8*)Kp;
    u16x8 vu = *(const u16x8*)(Kp + 512);   // V block
    float vv[8];
    float t = 0.f;
    #pragma unroll
    for (int c=0;c<8;c++){
      float ef = bf2f(eu[c]);
      float kf = bf2f(ku[c]) + ef;
      vv[c]    = bf2f(vu[c]) + ef;
      t += q[c]*kf;
    }
    t += __shfl_xor(t, 1, 64);
    t += __shfl_xor(t, 2, 64);
    t += __shfl_xor(t, 4, 64);
    float p = (j < end) ? __expf(t) : 0.f;
    l += p;
    #pragma unroll
    for (int c=0;c<8;c++) a[c] += p*vv[c];
  }

  // merge the two halves (each summed a disjoint subset of edges)
  l += __shfl_xor(l, 32, 64);
  #pragma unroll
  for (int c=0;c<8;c++) a[c] += __shfl_xor(a[c], 32, 64);

  float inv = (l > 0.f) ? 1.0f/l : 0.f;
  u16x8 su = *(const u16x8*)(base + 768 + c8);   // skip = x@Ws + bs
  float r[8];
  #pragma unroll
  for (int c=0;c<8;c++){
    float v = a[c]*inv + bf2f(su[c]);
    r[c] = relu ? fmaxf(v, 0.f) : v;
  }

  if (out_bf){
    if (!half){
      s16x8 o;
      #pragma unroll
      for (int c=0;c<8;c++) o[c] = f2bf(r[c]);
      *(s16x8*)(out_bf + (size_t)node*256 + c8) = o;
    }
  } else {
    float4 st = half ? make_float4(r[4],r[5],r[6],r[7])
                     : make_float4(r[0],r[1],r[2],r[3]);
    *(float4*)(out_f + (size_t)node*256 + c8 + half*4) = st;
  }
}

// ---------------- launch ----------------
extern "C" void kernel_launch(void* const* d_in, const int* in_sizes, int n_in,
                              void* d_out, int out_size, void* d_ws, size_t ws_size,
                              hipStream_t stream)
{
  const float* x     = (const float*)d_in[0];
  const int*   eidx  = (const int*)d_in[1];
  const float* eattr = (const float*)d_in[2];
  const float* Wq1=(const float*)d_in[3],  *bq1=(const float*)d_in[4];
  const float* Wk1=(const float*)d_in[5],  *bk1=(const float*)d_in[6];
  const float* Wv1=(const float*)d_in[7],  *bv1=(const float*)d_in[8];
  const float* We1=(const float*)d_in[9];
  const float* Ws1=(const float*)d_in[10], *bs1=(const float*)d_in[11];
  const float* Wq2=(const float*)d_in[12], *bq2=(const float*)d_in[13];
  const float* Wk2=(const float*)d_in[14], *bk2=(const float*)d_in[15];
  const float* Wv2=(const float*)d_in[16], *bv2=(const float*)d_in[17];
  const float* We2=(const float*)d_in[18];
  const float* Ws2=(const float*)d_in[19], *bs2=(const float*)d_in[20];

  char* ws = (char*)d_ws;
  size_t off = 0;
  auto alloc = [&](size_t bytes)->char*{
    char* p = ws + off; off = (off + bytes + 255) & ~(size_t)255; return p;
  };
  short* QKVS  = (short*)alloc((size_t)N_NODES*1024*2);
  short* Eemb  = (short*)alloc((size_t)MP_EDGE*256*2);
  short* x_bf  = (short*)alloc((size_t)MP_NODE*DIM*2);
  short* h_bf  = (short*)alloc((size_t)MP_NODE*DIM*2);
  short* e_bf  = (short*)alloc((size_t)MP_EDGE*EDP*2);
  short* WtN   = (short*)alloc((size_t)4*65536*2);
  short* WtE   = (short*)alloc((size_t)256*EDP*2);
  float* biasN = (float*)alloc((size_t)1024*4);
  int*   deg   = (int*)alloc((size_t)N_NODES*4);
  int*   rowptr= (int*)alloc((size_t)(N_NODES+1)*4);
  int*   cursor= (int*)alloc((size_t)N_NODES*4);
  int*   part  = (int*)alloc((size_t)256*4);
  int*   csrx  = (int*)alloc((size_t)N_EDGES*4);
  int*   eperm = (int*)alloc((size_t)N_EDGES*4);

  const int* srcp = eidx;
  const int* dstp = eidx + N_EDGES;

  const int EB = (N_EDGES + 255)/256;   // 977
  const int NB = (N_NODES + 255)/256;   // 196

  convert_x_kernel<<<MP_NODE*64/256,256,0,stream>>>(x, x_bf);
  convert_e_kernel<<<MP_EDGE/E_ROWS,256,0,stream>>>(eattr, e_bf);

  zero_ints<<<NB,256,0,stream>>>(deg, N_NODES);
  count_deg<<<EB,256,0,stream>>>(dstp, deg);
  scan_p1<<<SCAN_NBLK,256,0,stream>>>(deg, part);
  scan_p2<<<1,256,0,stream>>>(part);
  scan_p3<<<SCAN_NBLK,256,0,stream>>>(deg, part, rowptr, cursor);
  scatter_edges<<<EB,256,0,stream>>>(srcp, dstp, rowptr, cursor, csrx, eperm);

  // ---- conv1 ----
  transpose_node_w<<<1024,256,0,stream>>>(Wq1,Wk1,Wv1,Ws1,WtN);
  bias_cat_kernel<<<4,256,0,stream>>>(bq1,bk1,bv1,bs1,biasN);
  transpose_edge_w<<<224,256,0,stream>>>(We1,WtE);
  gemm_bt<DIM,1024,true,false><<<dim3(MP_NODE/128,8),256,0,stream>>>(x_bf, WtN, biasN, QKVS, N_NODES, nullptr);
  gemm_bt<EDP,256,false,true><<<dim3(MP_EDGE/128,2),256,0,stream>>>(e_bf, WtE, nullptr, Eemb, N_EDGES, eperm);
  edge_phase_kernel<<<MP_NODE/4,256,0,stream>>>(QKVS,Eemb,rowptr,csrx,h_bf,nullptr,1);

  // ---- conv2 ----
  transpose_node_w<<<1024,256,0,stream>>>(Wq2,Wk2,Wv2,Ws2,WtN);
  bias_cat_kernel<<<4,256,0,stream>>>(bq2,bk2,bv2,bs2,biasN);
  transpose_edge_w<<<224,256,0,stream>>>(We2,WtE);
  gemm_bt<DIM,1024,true,false><<<dim3(MP_NODE/128,8),256,0,stream>>>(h_bf, WtN, biasN, QKVS, N_NODES, nullptr);
  gemm_bt<EDP,256,false,true><<<dim3(MP_EDGE/128,2),256,0,stream>>>(e_bf, WtE, nullptr, Eemb, N_EDGES, eperm);
  edge_phase_kernel<<<N_NODES/4,256,0,stream>>>(QKVS,Eemb,rowptr,csrx,nullptr,(float*)d_out,0);
}

// Round 8
// 877.628 us; speedup vs baseline: 1.1423x; 1.0117x over previous
//
#include <hip/hip_runtime.h>

#define N_NODES 50000
#define N_EDGES 250000
#define DIM 256          // IN = OUT = H*C
#define ED 194           // edge feature dim
#define EDP 224          // padded to multiple of 32
#define MP_NODE 50048    // 391*128
#define MP_EDGE 250112   // 1954*128

typedef __bf16 bf16x8 __attribute__((ext_vector_type(8)));
typedef float f32x4 __attribute__((ext_vector_type(4)));
typedef short s16x8 __attribute__((ext_vector_type(8)));
typedef short s16x4 __attribute__((ext_vector_type(4)));
typedef unsigned short u16x8 __attribute__((ext_vector_type(8)));

__device__ __forceinline__ float bf2f(unsigned short b){
  union { unsigned int u; float f; } v; v.u = ((unsigned int)b)<<16; return v.f;
}
__device__ __forceinline__ short f2bf(float f){
  union { float f; unsigned int u; } v; v.f = f;
  unsigned int u = v.u;
  return (short)((u + 0x7fffu + ((u>>16)&1u))>>16);
}

// async global->LDS, 16B per lane. LDS dest = wave-uniform base + lane*16.
__device__ __forceinline__ void gload_lds16(const void* g, void* l){
  __builtin_amdgcn_global_load_lds(
      (const __attribute__((address_space(1))) unsigned int*)g,
      (__attribute__((address_space(3))) unsigned int*)l, 16, 0, 0);
}

// ---------------- input converts (fp32 -> bf16, padded) ----------------
// x rows are exactly DIM=256 floats -> flat layout identical in and out.
// Also zeroes deg[] (saves a launch; count_deg runs strictly later in-stream).
__global__ __launch_bounds__(256) void convert_x_kernel(
    const float* __restrict__ x, short* __restrict__ xb, int* __restrict__ deg)
{
  int idx = blockIdx.x*256 + threadIdx.x;       // MP_NODE*64 float4s total
  if (idx < N_NODES) deg[idx] = 0;
  s16x4 o;
  if (idx < N_NODES*64){
    float4 a = *(const float4*)(x + (size_t)idx*4);
    o[0]=f2bf(a.x); o[1]=f2bf(a.y); o[2]=f2bf(a.z); o[3]=f2bf(a.w);
  } else {
    o[0]=0; o[1]=0; o[2]=0; o[3]=0;
  }
  *(s16x4*)(xb + (size_t)idx*4) = o;
}

// Edge rows are 194 floats (776B, only 8B-aligned) -> stage 32 rows through
// LDS with dense flat float4 loads, then convert+pad with coalesced stores.
#define E_ROWS 32
__global__ __launch_bounds__(256) void convert_e_kernel(
    const float* __restrict__ ea, short* __restrict__ eb)
{
  __shared__ float lds[E_ROWS*ED];              // 6208 floats = 24832 B
  int row0 = blockIdx.x * E_ROWS;
  int tid = threadIdx.x;
  int base = row0 * ED;                         // float index of block start
  int valid = N_EDGES*ED - base;                // may be <=0 for pad blocks

  for (int i = tid; i < E_ROWS*ED/4; i += 256){
    float4 v;
    if (i*4 < valid) v = *(const float4*)(ea + base + i*4);
    else             v = make_float4(0.f,0.f,0.f,0.f);
    *(float4*)(lds + i*4) = v;
  }
  __syncthreads();

  for (int u = tid; u < E_ROWS*28; u += 256){
    int row = u / 28;
    int c8  = u - row*28;
    int col = c8*8;
    s16x8 o;
    if (col + 8 <= ED){
      #pragma unroll
      for (int j2=0;j2<4;j2++){
        float2 f = *(const float2*)(lds + row*ED + col + j2*2);
        o[j2*2]   = f2bf(f.x);
        o[j2*2+1] = f2bf(f.y);
      }
    } else {
      #pragma unroll
      for (int j=0;j<8;j++){
        int c = col + j;
        o[j] = (c < ED) ? f2bf(lds[row*ED + c]) : (short)0;
      }
    }
    *(s16x8*)(eb + (size_t)(row0+row)*EDP + col) = o;
  }
}

// ---------------- fused weight prep (one launch per conv) ----------------
// Replaces the 2B-stride-512B scattered stores of the naive transposes with
// 64x64 padded-LDS tiles: coalesced 4B reads, coalesced 8B writes.
// blocks 0..63: node-W transpose; 64..79: edge-W (zero-pad k>=ED); 80: bias.
__global__ __launch_bounds__(256) void prep_weights(
    const float* __restrict__ Wq, const float* __restrict__ Wk,
    const float* __restrict__ Wv, const float* __restrict__ Ws,
    const float* __restrict__ We,
    const float* __restrict__ b0, const float* __restrict__ b1,
    const float* __restrict__ b2, const float* __restrict__ b3,
    short* __restrict__ WtN, short* __restrict__ WtE, float* __restrict__ biasN)
{
  __shared__ short lds[64*65];
  int b = blockIdx.x, tid = threadIdx.x;
  if (b < 64){
    int mat = b>>4, tile = b&15;
    int i0 = (tile>>2)*64, o0 = (tile&3)*64;
    const float* W = (mat==0)?Wq:((mat==1)?Wk:((mat==2)?Wv:Ws));
    #pragma unroll
    for (int t=0;t<16;t++){
      int idx = t*256+tid; int r = idx>>6, c = idx&63;
      lds[r*65+c] = f2bf(W[(size_t)(i0+r)*256 + o0 + c]);
    }
    __syncthreads();
    #pragma unroll
    for (int t=0;t<4;t++){
      int idx = t*256+tid; int r = idx>>4, c4 = (idx&15)*4;
      s16x4 o;
      o[0]=lds[(c4+0)*65+r]; o[1]=lds[(c4+1)*65+r];
      o[2]=lds[(c4+2)*65+r]; o[3]=lds[(c4+3)*65+r];
      *(s16x4*)(WtN + (mat<<16) + (o0+r)*256 + i0 + c4) = o;
    }
  } else if (b < 80){
    int b2 = b-64;
    int k0 = (b2>>2)*64, o0 = (b2&3)*64;
    #pragma unroll
    for (int t=0;t<16;t++){
      int idx = t*256+tid; int r = idx>>6, c = idx&63;
      int k = k0+r;
      lds[r*65+c] = (k<ED) ? f2bf(We[(size_t)k*256 + o0 + c]) : (short)0;
    }
    __syncthreads();
    #pragma unroll
    for (int t=0;t<4;t++){
      int idx = t*256+tid; int r = idx>>4, c4 = (idx&15)*4;
      if (k0 + c4 < EDP){
        s16x4 o;
        o[0]=lds[(c4+0)*65+r]; o[1]=lds[(c4+1)*65+r];
        o[2]=lds[(c4+2)*65+r]; o[3]=lds[(c4+3)*65+r];
        *(s16x4*)(WtE + (o0+r)*EDP + k0 + c4) = o;
      }
    }
  } else {
    for (int t = tid; t < 1024; t += 256){
      const float* bb = (t<256)?b0:((t<512)?b1:((t<768)?b2:b3));
      biasN[t] = bb[t&255];
    }
  }
}

// ---------------- CSR build ----------------
__global__ __launch_bounds__(256) void count_deg(const int* __restrict__ dst, int* __restrict__ deg){
  int e = blockIdx.x*256 + threadIdx.x;
  if (e < N_EDGES) atomicAdd(&deg[dst[e]], 1);
}
#define SCAN_NBLK 196
__global__ __launch_bounds__(256) void scan_p1(const int* __restrict__ deg, int* __restrict__ part){
  int t = threadIdx.x;
  int i = blockIdx.x*256 + t;
  int v = (i<N_NODES)? deg[i] : 0;
  #pragma unroll
  for (int off=32; off; off>>=1) v += __shfl_xor(v, off, 64);
  __shared__ int s[4];
  if ((t&63)==0) s[t>>6] = v;
  __syncthreads();
  if (t==0) part[blockIdx.x] = s[0]+s[1]+s[2]+s[3];
}
__global__ __launch_bounds__(256) void scan_p2(int* __restrict__ part){
  __shared__ int s[256];
  int t = threadIdx.x;
  int v = (t<SCAN_NBLK)? part[t] : 0;
  s[t] = v; __syncthreads();
  for (int off=1; off<256; off<<=1){
    int x = (t>=off)? s[t-off] : 0;
    __syncthreads();
    s[t] += x;
    __syncthreads();
  }
  part[t] = (t==0)? 0 : s[t-1];
}
// also zeroes cursor
__global__ __launch_bounds__(256) void scan_p3(const int* __restrict__ deg,
    const int* __restrict__ part, int* __restrict__ rowptr, int* __restrict__ cursor){
  __shared__ int s[256];
  int t = threadIdx.x;
  int i = blockIdx.x*256 + t;
  int v = (i<N_NODES)? deg[i] : 0;
  s[t] = v; __syncthreads();
  for (int off=1; off<256; off<<=1){
    int x = (t>=off)? s[t-off] : 0;
    __syncthreads();
    s[t] += x;
    __syncthreads();
  }
  if (i < N_NODES){ rowptr[i+1] = part[blockIdx.x] + s[t]; cursor[i] = 0; }
  if (i == 0) rowptr[0] = 0;
}
// csr entries premultiplied to byte offsets: x = src*2048 (QKVS row), y = e*512 (Eemb row)
__global__ __launch_bounds__(256) void scatter_edges(
    const int* __restrict__ src, const int* __restrict__ dst,
    const int* __restrict__ rowptr, int* __restrict__ cursor, int2* __restrict__ csr)
{
  int e = blockIdx.x*256 + threadIdx.x;
  if (e < N_EDGES){
    int d = dst[e];
    int pos = atomicAdd(&cursor[d], 1);
    csr[rowptr[d] + pos] = make_int2(src[e]<<11, e<<9);
  }
}

// ---------------- tiled GEMM: out = A(bf16,[Mpad][K]) @ Bt^T (Bt=[N][K] bf16) ----
// r2-proven structure: 128x128 tile, 4 waves, row-major LDS [row][32k], staging
// 4-lane-contiguous-64B global reads.
// (Fragment-major staging REGRESSED r5: worse VMEM coalescing. 128x256 tile
// REGRESSED r4: occupancy collapse. Cooperative CSR REGRESSED r6: grid.sync
// ~20us each. Perm-gather A + CSR-ordered Eemb NEUTRAL r7. Keep this shape.)
template<int K, int NLD, bool HAS_BIAS>
__global__ __launch_bounds__(256) void gemm_bt(
    const short* __restrict__ A, const short* __restrict__ Bt,
    const float* __restrict__ bias, short* __restrict__ out, int M)
{
  __shared__ short As[128*32];
  __shared__ short Bs[128*32];
  int tid = threadIdx.x;
  int lane = tid & 63, wave = tid >> 6;
  int m0 = blockIdx.x*128, n0 = blockIdx.y*128;

  int srow = tid>>2, scol = (tid&3)*8;
  const short* gA = A + (size_t)(m0+srow)*K + scol;
  const short* gB = Bt + (size_t)(n0+srow)*K + scol;
  short* ldsA1 = As + wave*512;
  short* ldsA2 = As + 2048 + wave*512;
  short* ldsB1 = Bs + wave*512;
  short* ldsB2 = Bs + 2048 + wave*512;

  int wr = wave>>1, wc = wave&1;
  int fr = lane & 15;
  int kq = lane >> 4;
  f32x4 acc[4][4];
  #pragma unroll
  for (int a=0;a<4;a++)
    #pragma unroll
    for (int b=0;b<4;b++) acc[a][b] = (f32x4){0.f,0.f,0.f,0.f};

  for (int k0=0; k0<K; k0+=32){
    __syncthreads();
    gload_lds16(gA + k0,                ldsA1);
    gload_lds16(gA + (size_t)64*K + k0, ldsA2);
    gload_lds16(gB + k0,                ldsB1);
    gload_lds16(gB + (size_t)64*K + k0, ldsB2);
    __syncthreads();

    bf16x8 af[4], bf[4];
    const short* ar = As + (wr*64 + fr)*32 + kq*8;
    const short* br = Bs + (wc*64 + fr)*32 + kq*8;
    #pragma unroll
    for (int fm=0;fm<4;fm++) af[fm] = *(const bf16x8*)(ar + fm*512);
    #pragma unroll
    for (int fn=0;fn<4;fn++) bf[fn] = *(const bf16x8*)(br + fn*512);
    #pragma unroll
    for (int fm=0;fm<4;fm++)
      #pragma unroll
      for (int fn=0;fn<4;fn++)
        acc[fm][fn] = __builtin_amdgcn_mfma_f32_16x16x32_bf16(af[fm], bf[fn], acc[fm][fn], 0, 0, 0);
  }

  int cr = (lane>>4)*4;
  int cc = lane & 15;
  #pragma unroll
  for (int fm=0;fm<4;fm++){
    #pragma unroll
    for (int fn=0;fn<4;fn++){
      int col = n0 + wc*64 + fn*16 + cc;
      float bv = HAS_BIAS ? bias[col] : 0.f;
      #pragma unroll
      for (int i=0;i<4;i++){
        int row = m0 + wr*64 + fm*16 + cr + i;
        if (row < M) out[(size_t)row*NLD + col] = f2bf(acc[fm][fn][i] + bv);
      }
    }
  }
}

// ---------------- fused edge phase ----------------
// ONE WAVE PER NODE (4 nodes per block, no __syncthreads, no LDS merge).
// 32 lanes per edge, 8 channels per lane (16B loads), TWO edges in flight
// (half = lane>>5). Tail via clamped csr index + p=0. Cross-half merge via
// shfl_xor(32) — registers only.
// (4-edge unroll REGRESSED: +33% wasted clamped-duplicate loads at avg deg 5.)
__global__ __launch_bounds__(256) void edge_phase_kernel(
    const short* __restrict__ QKVS, const short* __restrict__ Eemb,
    const int* __restrict__ rowptr, const int2* __restrict__ csr,
    short* __restrict__ out_bf, float* __restrict__ out_f, int relu)
{
  int tid = threadIdx.x, wave = tid>>6, lane = tid&63;
  int node = blockIdx.x*4 + wave;
  if (node >= N_NODES){
    if (node < MP_NODE && out_bf){
      s16x4 z; z[0]=0; z[1]=0; z[2]=0; z[3]=0;
      *(s16x4*)(out_bf + (size_t)node*256 + lane*4) = z;
    }
    return;
  }
  int half = lane>>5;          // which edge of the pair
  int hl   = lane&31;          // channel-group 0..31 (8 ch each)
  int c8   = hl*8;
  const unsigned short* base = (const unsigned short*)QKVS + (size_t)node*1024;

  u16x8 qu = *(const u16x8*)(base + c8);
  float q[8];
  #pragma unroll
  for (int j=0;j<8;j++) q[j] = bf2f(qu[j])*0.125f;

  int beg = rowptr[node], end = rowptr[node+1];
  float l = 0.f;
  float a[8];
  #pragma unroll
  for (int j=0;j<8;j++) a[j] = 0.f;
  int kb = 512 + hl*16;        // K byte offset within QKVS row for this lane
  int ebo = hl*16;             // Eemb byte offset

  for (int idx = beg; idx < end; idx += 2){
    int j = idx + half;
    int jc = (j < end) ? j : (end-1);
    int2 se = csr[jc];         // .x = src*2048 bytes, .y = e*512 bytes
    const char* Kp = (const char*)QKVS + (unsigned)(se.x + kb);
    const char* Ep = (const char*)Eemb + (unsigned)(se.y + ebo);
    u16x8 ku = *(const u16x8*)Kp;
    u16x8 vu = *(const u16x8*)(Kp + 512);   // V block
    u16x8 eu = *(const u16x8*)Ep;
    float vv[8];
    float t = 0.f;
    #pragma unroll
    for (int c=0;c<8;c++){
      float ef = bf2f(eu[c]);
      float kf = bf2f(ku[c]) + ef;
      vv[c]    = bf2f(vu[c]) + ef;
      t += q[c]*kf;
    }
    t += __shfl_xor(t, 1, 64);
    t += __shfl_xor(t, 2, 64);
    t += __shfl_xor(t, 4, 64);
    float p = (j < end) ? __expf(t) : 0.f;
    l += p;
    #pragma unroll
    for (int c=0;c<8;c++) a[c] += p*vv[c];
  }

  // merge the two halves (each summed a disjoint subset of edges)
  l += __shfl_xor(l, 32, 64);
  #pragma unroll
  for (int c=0;c<8;c++) a[c] += __shfl_xor(a[c], 32, 64);

  float inv = (l > 0.f) ? 1.0f/l : 0.f;
  u16x8 su = *(const u16x8*)(base + 768 + c8);   // skip = x@Ws + bs
  float r[8];
  #pragma unroll
  for (int c=0;c<8;c++){
    float v = a[c]*inv + bf2f(su[c]);
    r[c] = relu ? fmaxf(v, 0.f) : v;
  }

  if (out_bf){
    if (!half){
      s16x8 o;
      #pragma unroll
      for (int c=0;c<8;c++) o[c] = f2bf(r[c]);
      *(s16x8*)(out_bf + (size_t)node*256 + c8) = o;
    }
  } else {
    float4 st = half ? make_float4(r[4],r[5],r[6],r[7])
                     : make_float4(r[0],r[1],r[2],r[3]);
    *(float4*)(out_f + (size_t)node*256 + c8 + half*4) = st;
  }
}

// ---------------- launch ----------------
extern "C" void kernel_launch(void* const* d_in, const int* in_sizes, int n_in,
                              void* d_out, int out_size, void* d_ws, size_t ws_size,
                              hipStream_t stream)
{
  const float* x     = (const float*)d_in[0];
  const int*   eidx  = (const int*)d_in[1];
  const float* eattr = (const float*)d_in[2];
  const float* Wq1=(const float*)d_in[3],  *bq1=(const float*)d_in[4];
  const float* Wk1=(const float*)d_in[5],  *bk1=(const float*)d_in[6];
  const float* Wv1=(const float*)d_in[7],  *bv1=(const float*)d_in[8];
  const float* We1=(const float*)d_in[9];
  const float* Ws1=(const float*)d_in[10], *bs1=(const float*)d_in[11];
  const float* Wq2=(const float*)d_in[12], *bq2=(const float*)d_in[13];
  const float* Wk2=(const float*)d_in[14], *bk2=(const float*)d_in[15];
  const float* Wv2=(const float*)d_in[16], *bv2=(const float*)d_in[17];
  const float* We2=(const float*)d_in[18];
  const float* Ws2=(const float*)d_in[19], *bs2=(const float*)d_in[20];

  char* ws = (char*)d_ws;
  size_t off = 0;
  auto alloc = [&](size_t bytes)->char*{
    char* p = ws + off; off = (off + bytes + 255) & ~(size_t)255; return p;
  };
  short* QKVS  = (short*)alloc((size_t)N_NODES*1024*2);
  short* Eemb  = (short*)alloc((size_t)N_EDGES*256*2);
  short* x_bf  = (short*)alloc((size_t)MP_NODE*DIM*2);
  short* h_bf  = (short*)alloc((size_t)MP_NODE*DIM*2);
  short* e_bf  = (short*)alloc((size_t)MP_EDGE*EDP*2);
  short* WtN   = (short*)alloc((size_t)4*65536*2);
  short* WtE   = (short*)alloc((size_t)256*EDP*2);
  float* biasN = (float*)alloc((size_t)1024*4);
  int*   deg   = (int*)alloc((size_t)N_NODES*4);
  int*   rowptr= (int*)alloc((size_t)(N_NODES+1)*4);
  int*   cursor= (int*)alloc((size_t)N_NODES*4);
  int*   part  = (int*)alloc((size_t)256*4);
  int2*  csr   = (int2*)alloc((size_t)N_EDGES*8);

  const int* srcp = eidx;
  const int* dstp = eidx + N_EDGES;

  const int EB = (N_EDGES + 255)/256;   // 977

  convert_x_kernel<<<MP_NODE*64/256,256,0,stream>>>(x, x_bf, deg);
  convert_e_kernel<<<MP_EDGE/E_ROWS,256,0,stream>>>(eattr, e_bf);

  count_deg<<<EB,256,0,stream>>>(dstp, deg);
  scan_p1<<<SCAN_NBLK,256,0,stream>>>(deg, part);
  scan_p2<<<1,256,0,stream>>>(part);
  scan_p3<<<SCAN_NBLK,256,0,stream>>>(deg, part, rowptr, cursor);
  scatter_edges<<<EB,256,0,stream>>>(srcp, dstp, rowptr, cursor, csr);

  // ---- conv1 ----
  prep_weights<<<81,256,0,stream>>>(Wq1,Wk1,Wv1,Ws1,We1,bq1,bk1,bv1,bs1,WtN,WtE,biasN);
  gemm_bt<DIM,1024,true><<<dim3(MP_NODE/128,8),256,0,stream>>>(x_bf, WtN, biasN, QKVS, N_NODES);
  gemm_bt<EDP,256,false><<<dim3(MP_EDGE/128,2),256,0,stream>>>(e_bf, WtE, nullptr, Eemb, N_EDGES);
  edge_phase_kernel<<<MP_NODE/4,256,0,stream>>>(QKVS,Eemb,rowptr,csr,h_bf,nullptr,1);

  // ---- conv2 ----
  prep_weights<<<81,256,0,stream>>>(Wq2,Wk2,Wv2,Ws2,We2,bq2,bk2,bv2,bs2,WtN,WtE,biasN);
  gemm_bt<DIM,1024,true><<<dim3(MP_NODE/128,8),256,0,stream>>>(h_bf, WtN, biasN, QKVS, N_NODES);
  gemm_bt<EDP,256,false><<<dim3(MP_EDGE/128,2),256,0,stream>>>(e_bf, WtE, nullptr, Eemb, N_EDGES);
  edge_phase_kernel<<<N_NODES/4,256,0,stream>>>(QKVS,Eemb,rowptr,csr,nullptr,(float*)d_out,0);
}

// Round 9
// 849.960 us; speedup vs baseline: 1.1795x; 1.0326x over previous
//
#include <hip/hip_runtime.h>

#define N_NODES 50000
#define N_EDGES 250000
#define DIM 256          // IN = OUT = H*C
#define ED 194           // edge feature dim
#define EDP 224          // padded to multiple of 32
#define MP_NODE 50048    // 391*128
#define MP_EDGE 250112   // 1954*128

typedef __bf16 bf16x8 __attribute__((ext_vector_type(8)));
typedef float f32x4 __attribute__((ext_vector_type(4)));
typedef short s16x8 __attribute__((ext_vector_type(8)));
typedef short s16x4 __attribute__((ext_vector_type(4)));
typedef unsigned short u16x8 __attribute__((ext_vector_type(8)));

__device__ __forceinline__ float bf2f(unsigned short b){
  union { unsigned int u; float f; } v; v.u = ((unsigned int)b)<<16; return v.f;
}
__device__ __forceinline__ short f2bf(float f){
  union { float f; unsigned int u; } v; v.f = f;
  unsigned int u = v.u;
  return (short)((u + 0x7fffu + ((u>>16)&1u))>>16);
}

// async global->LDS, 16B per lane. LDS dest = wave-uniform base + lane*16.
__device__ __forceinline__ void gload_lds16(const void* g, void* l){
  __builtin_amdgcn_global_load_lds(
      (const __attribute__((address_space(1))) unsigned int*)g,
      (__attribute__((address_space(3))) unsigned int*)l, 16, 0, 0);
}

// ---------------- input converts (fp32 -> bf16, padded) ----------------
// x rows are exactly DIM=256 floats -> flat layout identical in and out.
// Also zeroes deg[] (saves a launch; count_deg runs strictly later in-stream).
__global__ __launch_bounds__(256) void convert_x_kernel(
    const float* __restrict__ x, short* __restrict__ xb, int* __restrict__ deg)
{
  int idx = blockIdx.x*256 + threadIdx.x;       // MP_NODE*64 float4s total
  if (idx < N_NODES) deg[idx] = 0;
  s16x4 o;
  if (idx < N_NODES*64){
    float4 a = *(const float4*)(x + (size_t)idx*4);
    o[0]=f2bf(a.x); o[1]=f2bf(a.y); o[2]=f2bf(a.z); o[3]=f2bf(a.w);
  } else {
    o[0]=0; o[1]=0; o[2]=0; o[3]=0;
  }
  *(s16x4*)(xb + (size_t)idx*4) = o;
}

// Edge rows are 194 floats (776B, only 8B-aligned) -> stage 32 rows through
// LDS with dense flat float4 loads, then convert+pad with coalesced stores.
#define E_ROWS 32
__global__ __launch_bounds__(256) void convert_e_kernel(
    const float* __restrict__ ea, short* __restrict__ eb)
{
  __shared__ float lds[E_ROWS*ED];              // 6208 floats = 24832 B
  int row0 = blockIdx.x * E_ROWS;
  int tid = threadIdx.x;
  int base = row0 * ED;                         // float index of block start
  int valid = N_EDGES*ED - base;                // may be <=0 for pad blocks

  for (int i = tid; i < E_ROWS*ED/4; i += 256){
    float4 v;
    if (i*4 < valid) v = *(const float4*)(ea + base + i*4);
    else             v = make_float4(0.f,0.f,0.f,0.f);
    *(float4*)(lds + i*4) = v;
  }
  __syncthreads();

  for (int u = tid; u < E_ROWS*28; u += 256){
    int row = u / 28;
    int c8  = u - row*28;
    int col = c8*8;
    s16x8 o;
    if (col + 8 <= ED){
      #pragma unroll
      for (int j2=0;j2<4;j2++){
        float2 f = *(const float2*)(lds + row*ED + col + j2*2);
        o[j2*2]   = f2bf(f.x);
        o[j2*2+1] = f2bf(f.y);
      }
    } else {
      #pragma unroll
      for (int j=0;j<8;j++){
        int c = col + j;
        o[j] = (c < ED) ? f2bf(lds[row*ED + c]) : (short)0;
      }
    }
    *(s16x8*)(eb + (size_t)(row0+row)*EDP + col) = o;
  }
}

// ---------------- fused weight prep: BOTH convs, one launch (162 blocks) ----
// blocks   0.. 63 : conv1 node-W 64x64 padded-LDS tile transpose
// blocks  64..127 : conv2 node-W
// blocks 128..159 : edge-W BOTH convs -> WtE[512][EDP] (rows 0-255 = We1^T,
//                   rows 256-511 = We2^T), zero-pad k>=ED
// blocks 160,161  : bias concat conv1 / conv2
__global__ __launch_bounds__(256) void prep_weights_all(
    const float* __restrict__ Wq1, const float* __restrict__ Wk1,
    const float* __restrict__ Wv1, const float* __restrict__ Ws1,
    const float* __restrict__ We1,
    const float* __restrict__ bq1, const float* __restrict__ bk1,
    const float* __restrict__ bv1, const float* __restrict__ bs1,
    const float* __restrict__ Wq2, const float* __restrict__ Wk2,
    const float* __restrict__ Wv2, const float* __restrict__ Ws2,
    const float* __restrict__ We2,
    const float* __restrict__ bq2, const float* __restrict__ bk2,
    const float* __restrict__ bv2, const float* __restrict__ bs2,
    short* __restrict__ WtN1, short* __restrict__ WtN2,
    short* __restrict__ WtE, float* __restrict__ biasN1, float* __restrict__ biasN2)
{
  __shared__ short lds[64*65];
  int b = blockIdx.x, tid = threadIdx.x;
  if (b < 128){
    int conv = b>>6, bb = b&63;
    int mat = bb>>4, tile = bb&15;
    int i0 = (tile>>2)*64, o0 = (tile&3)*64;
    const float* W = conv ? ((mat==0)?Wq2:((mat==1)?Wk2:((mat==2)?Wv2:Ws2)))
                          : ((mat==0)?Wq1:((mat==1)?Wk1:((mat==2)?Wv1:Ws1)));
    short* WtN = conv ? WtN2 : WtN1;
    #pragma unroll
    for (int t=0;t<16;t++){
      int idx = t*256+tid; int r = idx>>6, c = idx&63;
      lds[r*65+c] = f2bf(W[(size_t)(i0+r)*256 + o0 + c]);
    }
    __syncthreads();
    #pragma unroll
    for (int t=0;t<4;t++){
      int idx = t*256+tid; int r = idx>>4, c4 = (idx&15)*4;
      s16x4 o;
      o[0]=lds[(c4+0)*65+r]; o[1]=lds[(c4+1)*65+r];
      o[2]=lds[(c4+2)*65+r]; o[3]=lds[(c4+3)*65+r];
      *(s16x4*)(WtN + (mat<<16) + (o0+r)*256 + i0 + c4) = o;
    }
  } else if (b < 160){
    int b2 = b-128;                 // 32 blocks: 4 k-tiles x 8 o-tiles
    int k0 = (b2>>3)*64, o0 = (b2&7)*64;   // o0 in 0..511
    const float* We = (o0 < 256) ? We1 : We2;
    int oc = o0 & 255;
    #pragma unroll
    for (int t=0;t<16;t++){
      int idx = t*256+tid; int r = idx>>6, c = idx&63;
      int k = k0+r;
      lds[r*65+c] = (k<ED) ? f2bf(We[(size_t)k*256 + oc + c]) : (short)0;
    }
    __syncthreads();
    #pragma unroll
    for (int t=0;t<4;t++){
      int idx = t*256+tid; int r = idx>>4, c4 = (idx&15)*4;
      if (k0 + c4 < EDP){
        s16x4 o;
        o[0]=lds[(c4+0)*65+r]; o[1]=lds[(c4+1)*65+r];
        o[2]=lds[(c4+2)*65+r]; o[3]=lds[(c4+3)*65+r];
        *(s16x4*)(WtE + (size_t)(o0+r)*EDP + k0 + c4) = o;
      }
    }
  } else {
    int conv = b - 160;
    float* biasN = conv ? biasN2 : biasN1;
    for (int t = tid; t < 1024; t += 256){
      const float* bb = conv ? ((t<256)?bq2:((t<512)?bk2:((t<768)?bv2:bs2)))
                             : ((t<256)?bq1:((t<512)?bk1:((t<768)?bv1:bs1)));
      biasN[t] = bb[t&255];
    }
  }
}

// ---------------- CSR build ----------------
__global__ __launch_bounds__(256) void count_deg(const int* __restrict__ dst, int* __restrict__ deg){
  int e = blockIdx.x*256 + threadIdx.x;
  if (e < N_EDGES) atomicAdd(&deg[dst[e]], 1);
}
#define SCAN_NBLK 196
__global__ __launch_bounds__(256) void scan_p1(const int* __restrict__ deg, int* __restrict__ part){
  int t = threadIdx.x;
  int i = blockIdx.x*256 + t;
  int v = (i<N_NODES)? deg[i] : 0;
  #pragma unroll
  for (int off=32; off; off>>=1) v += __shfl_xor(v, off, 64);
  __shared__ int s[4];
  if ((t&63)==0) s[t>>6] = v;
  __syncthreads();
  if (t==0) part[blockIdx.x] = s[0]+s[1]+s[2]+s[3];
}
__global__ __launch_bounds__(256) void scan_p2(int* __restrict__ part){
  __shared__ int s[256];
  int t = threadIdx.x;
  int v = (t<SCAN_NBLK)? part[t] : 0;
  s[t] = v; __syncthreads();
  for (int off=1; off<256; off<<=1){
    int x = (t>=off)? s[t-off] : 0;
    __syncthreads();
    s[t] += x;
    __syncthreads();
  }
  part[t] = (t==0)? 0 : s[t-1];
}
// also zeroes cursor
__global__ __launch_bounds__(256) void scan_p3(const int* __restrict__ deg,
    const int* __restrict__ part, int* __restrict__ rowptr, int* __restrict__ cursor){
  __shared__ int s[256];
  int t = threadIdx.x;
  int i = blockIdx.x*256 + t;
  int v = (i<N_NODES)? deg[i] : 0;
  s[t] = v; __syncthreads();
  for (int off=1; off<256; off<<=1){
    int x = (t>=off)? s[t-off] : 0;
    __syncthreads();
    s[t] += x;
    __syncthreads();
  }
  if (i < N_NODES){ rowptr[i+1] = part[blockIdx.x] + s[t]; cursor[i] = 0; }
  if (i == 0) rowptr[0] = 0;
}
// csr entries premultiplied to byte offsets:
//   x = src*2048 (QKVS row), y = e*1024 (Eemb row, 512 bf16 cols for both convs)
__global__ __launch_bounds__(256) void scatter_edges(
    const int* __restrict__ src, const int* __restrict__ dst,
    const int* __restrict__ rowptr, int* __restrict__ cursor, int2* __restrict__ csr)
{
  int e = blockIdx.x*256 + threadIdx.x;
  if (e < N_EDGES){
    int d = dst[e];
    int pos = atomicAdd(&cursor[d], 1);
    csr[rowptr[d] + pos] = make_int2(src[e]<<11, e<<10);
  }
}

// ---------------- tiled GEMM: out = A(bf16,[Mpad][K]) @ Bt^T (Bt=[N][K] bf16) ----
// r2-proven structure: 128x128 tile, 4 waves, row-major LDS [row][32k], staging
// 4-lane-contiguous-64B global reads.
// (Fragment-major staging REGRESSED r5. 128x256 tile REGRESSED r4. Cooperative
// CSR REGRESSED r6. Perm-gather A NEUTRAL r7. Keep this shape.)
template<int K, int NLD, bool HAS_BIAS>
__global__ __launch_bounds__(256) void gemm_bt(
    const short* __restrict__ A, const short* __restrict__ Bt,
    const float* __restrict__ bias, short* __restrict__ out, int M)
{
  __shared__ short As[128*32];
  __shared__ short Bs[128*32];
  int tid = threadIdx.x;
  int lane = tid & 63, wave = tid >> 6;
  int m0 = blockIdx.x*128, n0 = blockIdx.y*128;

  int srow = tid>>2, scol = (tid&3)*8;
  const short* gA = A + (size_t)(m0+srow)*K + scol;
  const short* gB = Bt + (size_t)(n0+srow)*K + scol;
  short* ldsA1 = As + wave*512;
  short* ldsA2 = As + 2048 + wave*512;
  short* ldsB1 = Bs + wave*512;
  short* ldsB2 = Bs + 2048 + wave*512;

  int wr = wave>>1, wc = wave&1;
  int fr = lane & 15;
  int kq = lane >> 4;
  f32x4 acc[4][4];
  #pragma unroll
  for (int a=0;a<4;a++)
    #pragma unroll
    for (int b=0;b<4;b++) acc[a][b] = (f32x4){0.f,0.f,0.f,0.f};

  for (int k0=0; k0<K; k0+=32){
    __syncthreads();
    gload_lds16(gA + k0,                ldsA1);
    gload_lds16(gA + (size_t)64*K + k0, ldsA2);
    gload_lds16(gB + k0,                ldsB1);
    gload_lds16(gB + (size_t)64*K + k0, ldsB2);
    __syncthreads();

    bf16x8 af[4], bf[4];
    const short* ar = As + (wr*64 + fr)*32 + kq*8;
    const short* br = Bs + (wc*64 + fr)*32 + kq*8;
    #pragma unroll
    for (int fm=0;fm<4;fm++) af[fm] = *(const bf16x8*)(ar + fm*512);
    #pragma unroll
    for (int fn=0;fn<4;fn++) bf[fn] = *(const bf16x8*)(br + fn*512);
    #pragma unroll
    for (int fm=0;fm<4;fm++)
      #pragma unroll
      for (int fn=0;fn<4;fn++)
        acc[fm][fn] = __builtin_amdgcn_mfma_f32_16x16x32_bf16(af[fm], bf[fn], acc[fm][fn], 0, 0, 0);
  }

  int cr = (lane>>4)*4;
  int cc = lane & 15;
  #pragma unroll
  for (int fm=0;fm<4;fm++){
    #pragma unroll
    for (int fn=0;fn<4;fn++){
      int col = n0 + wc*64 + fn*16 + cc;
      float bv = HAS_BIAS ? bias[col] : 0.f;
      #pragma unroll
      for (int i=0;i<4;i++){
        int row = m0 + wr*64 + fm*16 + cr + i;
        if (row < M) out[(size_t)row*NLD + col] = f2bf(acc[fm][fn][i] + bv);
      }
    }
  }
}

// ---------------- fused edge phase ----------------
// ONE WAVE PER NODE (4 nodes per block, no __syncthreads, no LDS merge).
// 32 lanes per edge, 8 channels per lane (16B loads), TWO edges in flight
// (half = lane>>5). The csr entry for the NEXT iteration is software-prefetched
// so its ~200cy L2 latency overlaps the current K/V/E gathers (zero extra
// gather loads — unlike the failed 4-edge unroll). Tail via clamped csr index
// + p=0. Cross-half merge via shfl_xor(32) — registers only.
// Eemb rows are 512 bf16 (both convs); caller passes base +0 (conv1) or +256.
__global__ __launch_bounds__(256) void edge_phase_kernel(
    const short* __restrict__ QKVS, const short* __restrict__ Eemb,
    const int* __restrict__ rowptr, const int2* __restrict__ csr,
    short* __restrict__ out_bf, float* __restrict__ out_f, int relu)
{
  int tid = threadIdx.x, wave = tid>>6, lane = tid&63;
  int node = blockIdx.x*4 + wave;
  if (node >= N_NODES){
    if (node < MP_NODE && out_bf){
      s16x4 z; z[0]=0; z[1]=0; z[2]=0; z[3]=0;
      *(s16x4*)(out_bf + (size_t)node*256 + lane*4) = z;
    }
    return;
  }
  int half = lane>>5;          // which edge of the pair
  int hl   = lane&31;          // channel-group 0..31 (8 ch each)
  int c8   = hl*8;
  const unsigned short* base = (const unsigned short*)QKVS + (size_t)node*1024;

  u16x8 qu = *(const u16x8*)(base + c8);
  float q[8];
  #pragma unroll
  for (int j=0;j<8;j++) q[j] = bf2f(qu[j])*0.125f;

  int beg = rowptr[node], end = rowptr[node+1];
  float l = 0.f;
  float a[8];
  #pragma unroll
  for (int j=0;j<8;j++) a[j] = 0.f;
  int kb = 512 + hl*16;        // K byte offset within QKVS row for this lane
  int ebo = hl*16;             // Eemb byte offset within row-half

  if (beg < end){
    int j0 = beg + half;
    int2 se = csr[(j0 < end) ? j0 : (end-1)];
    for (int idx = beg; idx < end; idx += 2){
      int jn = idx + 2 + half;
      int2 se_n = csr[(jn < end) ? jn : (end-1)];   // prefetch next iteration
      int j = idx + half;
      const char* Kp = (const char*)QKVS + (unsigned)(se.x + kb);
      const char* Ep = (const char*)Eemb + (unsigned)(se.y + ebo);
      u16x8 ku = *(const u16x8*)Kp;
      u16x8 vu = *(const u16x8*)(Kp + 512);   // V block
      u16x8 eu = *(const u16x8*)Ep;
      float vv[8];
      float t = 0.f;
      #pragma unroll
      for (int c=0;c<8;c++){
        float ef = bf2f(eu[c]);
        float kf = bf2f(ku[c]) + ef;
        vv[c]    = bf2f(vu[c]) + ef;
        t += q[c]*kf;
      }
      t += __shfl_xor(t, 1, 64);
      t += __shfl_xor(t, 2, 64);
      t += __shfl_xor(t, 4, 64);
      float p = (j < end) ? __expf(t) : 0.f;
      l += p;
      #pragma unroll
      for (int c=0;c<8;c++) a[c] += p*vv[c];
      se = se_n;
    }
  }

  // merge the two halves (each summed a disjoint subset of edges)
  l += __shfl_xor(l, 32, 64);
  #pragma unroll
  for (int c=0;c<8;c++) a[c] += __shfl_xor(a[c], 32, 64);

  float inv = (l > 0.f) ? 1.0f/l : 0.f;
  u16x8 su = *(const u16x8*)(base + 768 + c8);   // skip = x@Ws + bs
  float r[8];
  #pragma unroll
  for (int c=0;c<8;c++){
    float v = a[c]*inv + bf2f(su[c]);
    r[c] = relu ? fmaxf(v, 0.f) : v;
  }

  if (out_bf){
    if (!half){
      s16x8 o;
      #pragma unroll
      for (int c=0;c<8;c++) o[c] = f2bf(r[c]);
      *(s16x8*)(out_bf + (size_t)node*256 + c8) = o;
    }
  } else {
    float4 st = half ? make_float4(r[4],r[5],r[6],r[7])
                     : make_float4(r[0],r[1],r[2],r[3]);
    *(float4*)(out_f + (size_t)node*256 + c8 + half*4) = st;
  }
}

// ---------------- launch ----------------
extern "C" void kernel_launch(void* const* d_in, const int* in_sizes, int n_in,
                              void* d_out, int out_size, void* d_ws, size_t ws_size,
                              hipStream_t stream)
{
  const float* x     = (const float*)d_in[0];
  const int*   eidx  = (const int*)d_in[1];
  const float* eattr = (const float*)d_in[2];
  const float* Wq1=(const float*)d_in[3],  *bq1=(const float*)d_in[4];
  const float* Wk1=(const float*)d_in[5],  *bk1=(const float*)d_in[6];
  const float* Wv1=(const float*)d_in[7],  *bv1=(const float*)d_in[8];
  const float* We1=(const float*)d_in[9];
  const float* Ws1=(const float*)d_in[10], *bs1=(const float*)d_in[11];
  const float* Wq2=(const float*)d_in[12], *bq2=(const float*)d_in[13];
  const float* Wk2=(const float*)d_in[14], *bk2=(const float*)d_in[15];
  const float* Wv2=(const float*)d_in[16], *bv2=(const float*)d_in[17];
  const float* We2=(const float*)d_in[18];
  const float* Ws2=(const float*)d_in[19], *bs2=(const float*)d_in[20];

  char* ws = (char*)d_ws;
  size_t off = 0;
  auto alloc = [&](size_t bytes)->char*{
    char* p = ws + off; off = (off + bytes + 255) & ~(size_t)255; return p;
  };
  short* QKVS  = (short*)alloc((size_t)N_NODES*1024*2);
  short* Eemb  = (short*)alloc((size_t)MP_EDGE*512*2);   // 512 cols: conv1|conv2
  short* x_bf  = (short*)alloc((size_t)MP_NODE*DIM*2);
  short* h_bf  = (short*)alloc((size_t)MP_NODE*DIM*2);
  short* e_bf  = (short*)alloc((size_t)MP_EDGE*EDP*2);
  short* WtN1  = (short*)alloc((size_t)4*65536*2);
  short* WtN2  = (short*)alloc((size_t)4*65536*2);
  short* WtE   = (short*)alloc((size_t)512*EDP*2);
  float* biasN1= (float*)alloc((size_t)1024*4);
  float* biasN2= (float*)alloc((size_t)1024*4);
  int*   deg   = (int*)alloc((size_t)N_NODES*4);
  int*   rowptr= (int*)alloc((size_t)(N_NODES+1)*4);
  int*   cursor= (int*)alloc((size_t)N_NODES*4);
  int*   part  = (int*)alloc((size_t)256*4);
  int2*  csr   = (int2*)alloc((size_t)N_EDGES*8);

  const int* srcp = eidx;
  const int* dstp = eidx + N_EDGES;

  const int EB = (N_EDGES + 255)/256;   // 977

  convert_x_kernel<<<MP_NODE*64/256,256,0,stream>>>(x, x_bf, deg);
  convert_e_kernel<<<MP_EDGE/E_ROWS,256,0,stream>>>(eattr, e_bf);

  count_deg<<<EB,256,0,stream>>>(dstp, deg);
  scan_p1<<<SCAN_NBLK,256,0,stream>>>(deg, part);
  scan_p2<<<1,256,0,stream>>>(part);
  scan_p3<<<SCAN_NBLK,256,0,stream>>>(deg, part, rowptr, cursor);
  scatter_edges<<<EB,256,0,stream>>>(srcp, dstp, rowptr, cursor, csr);

  prep_weights_all<<<162,256,0,stream>>>(
      Wq1,Wk1,Wv1,Ws1,We1,bq1,bk1,bv1,bs1,
      Wq2,Wk2,Wv2,Ws2,We2,bq2,bk2,bv2,bs2,
      WtN1,WtN2,WtE,biasN1,biasN2);

  // merged edge GEMM: Eemb[:,0:256]=e@We1, [:,256:512]=e@We2 — e_bf read ONCE
  gemm_bt<EDP,512,false><<<dim3(MP_EDGE/128,4),256,0,stream>>>(e_bf, WtE, nullptr, Eemb, N_EDGES);

  // ---- conv1 ----
  gemm_bt<DIM,1024,true><<<dim3(MP_NODE/128,8),256,0,stream>>>(x_bf, WtN1, biasN1, QKVS, N_NODES);
  edge_phase_kernel<<<MP_NODE/4,256,0,stream>>>(QKVS,Eemb,rowptr,csr,h_bf,nullptr,1);

  // ---- conv2 ----
  gemm_bt<DIM,1024,true><<<dim3(MP_NODE/128,8),256,0,stream>>>(h_bf, WtN2, biasN2, QKVS, N_NODES);
  edge_phase_kernel<<<N_NODES/4,256,0,stream>>>(QKVS,Eemb+256,rowptr,csr,nullptr,(float*)d_out,0);
}